// Round 4
// baseline (250.061 us; speedup 1.0000x reference)
//
#include <hip/hip_runtime.h>
#include <math.h>

#define GAMMA 0.3f
#define EPS 1e-6f
#define B_SZ 16
#define NH 32
#define KF 32768
#define KI 16384
#define KHEADS 7   // ceil(0.2 * 32)

typedef float f4v __attribute__((ext_vector_type(4)));

// ---- workspace layout (float indices) ----
constexpr int OFF_MU    = 0;                    // 64  (b*4+f)
constexpr int OFF_SD    = 64;                   // 64
constexpr int OFF_RAWS  = 128;                  // 512  raw softmax denom per (b,h)
constexpr int OFF_RAWP  = 640;                  // 512  raw pos numerator
constexpr int OFF_RAWN  = 1152;                 // 512  raw neg numerator
constexpr int OFF_GP    = 1664;                 // 512  per-(b,h) pos gamma (0 or GAMMA)
constexpr int OFF_GN    = 2176;                 // 512  per-(b,h) neg gamma
constexpr int IOFF_CNT  = 2688;                 // 16 ints: per-batch completion counters
constexpr int IOFF_BSUM = 2720;                 // 256 ints (per-2048-chunk mask counts)
constexpr int OFF_RFF   = 4096;                 // B*KF  rf expanded: rf>=0 on-mask, -1 off-mask

// LESSONS (journal):
//  prev-R6: cooperative grid.sync() fusion = ~120 µs barrier cost. NO.
//  R1: per-batch spin barrier + launch_bounds(256,4) regressed (VGPR cap 64
//      -> attn re-loaded; barrier serialized tail). NO spin/global sync.
//  R2: fusing stats into expand (redundant serial per-block stats) = 47.8 µs,
//      9% occupancy, latency-bound. Stats stay parallel; 4-dispatch skeleton.
//  R3 (best, 146.8): shuffle reductions, 2048-blk scores, swizzled NT k_out.
//  Overhead model: ~82 µs harness fills (2x41, immovable) + kernels + gaps.
//  R4: "last-block epilogue" in k_scores computes head roles once per batch
//      (no spin — the 128th arriving block just does extra work); k_out
//      becomes pure streaming (no LDS/syncthreads preamble).

// ---- blocks [0,64): per-(b,feat) mean/(std+eps) via wave-shuffle reduce;
//      blocks [64,320): 2048-int mask chunk counts (first 6 also zero accums,
//      block 70 zeroes the completion counters) ----
__global__ __launch_bounds__(256) void k_stats_cnt(const float* __restrict__ fC,
        const float* __restrict__ fA, const float* __restrict__ fD,
        const float* __restrict__ fB, const int* __restrict__ mask,
        float* __restrict__ ws) {
    int bid = blockIdx.x, t = threadIdx.x;
    int lane = t & 63, wid = t >> 6;
    if (bid < 64) {
        int b = bid >> 2, f = bid & 3;
        const float* src;
        if (f == 0) src = fC; else if (f == 1) src = fA; else if (f == 2) src = fD; else src = fB;
        src += (size_t)b * KI;
        double s = 0.0, s2 = 0.0;
        #pragma unroll 4
        for (int i = t; i < KI / 4; i += 256) {
            float4 v = ((const float4*)src)[i];
            s  += (double)v.x + (double)v.y + (double)v.z + (double)v.w;
            s2 += (double)v.x * v.x + (double)v.y * v.y + (double)v.z * v.z + (double)v.w * v.w;
        }
        #pragma unroll
        for (int off = 32; off > 0; off >>= 1) {
            s  += __shfl_down(s, off);
            s2 += __shfl_down(s2, off);
        }
        __shared__ double w1[4], w2[4];
        if (lane == 0) { w1[wid] = s; w2[wid] = s2; }
        __syncthreads();
        if (t == 0) {
            double S1 = w1[0] + w1[1] + w1[2] + w1[3];
            double S2 = w2[0] + w2[1] + w2[2] + w2[3];
            double mu  = S1 * (1.0 / KI);
            double var = fmax(S2 * (1.0 / KI) - mu * mu, 0.0);
            ws[OFF_MU + bid] = (float)mu;
            ws[OFF_SD + bid] = (float)(sqrt(var) + (double)EPS);
        }
    } else {
        int cblk = bid - 64;                     // 0..255, 2048 ints each
        if (cblk < 6) ws[OFF_RAWS + cblk * 256 + t] = 0.f;   // zero 1536 accum floats
        if (cblk == 6 && t < 16) ((int*)ws)[IOFF_CNT + t] = 0;
        const int* mrow = mask + (size_t)cblk * 2048;
        int4 m0 = *(const int4*)(mrow + t * 8);
        int4 m1 = *(const int4*)(mrow + t * 8 + 4);
        int cnt = (m0.x != 0) + (m0.y != 0) + (m0.z != 0) + (m0.w != 0)
                + (m1.x != 0) + (m1.y != 0) + (m1.z != 0) + (m1.w != 0);
        #pragma unroll
        for (int off = 32; off > 0; off >>= 1) cnt += __shfl_down(cnt, off);
        __shared__ int wc[4];
        if (lane == 0) wc[wid] = cnt;
        __syncthreads();
        if (t == 0) ((int*)ws)[IOFF_BSUM + cblk] = wc[0] + wc[1] + wc[2] + wc[3];
    }
}

// ---- fused rf-compute + expand-to-full-K (rf on-mask, -1 off-mask).
//      Image-token ranks of block (b,c) form the contiguous feat range
//      [boff, boff+total); wave-shuffle scan for local ranks. ----
__global__ __launch_bounds__(256) void k_rf_expand(const float* __restrict__ fC,
        const float* __restrict__ fA, const float* __restrict__ fD,
        const float* __restrict__ fB, const int* __restrict__ mask,
        float* __restrict__ ws) {
    __shared__ int sb[16];
    __shared__ int wsum[4];
    __shared__ float rfbuf[2048];
    int blk = blockIdx.x, t = threadIdx.x;       // blk = b*16 + c
    int b = blk >> 4, c = blk & 15;
    int lane = t & 63, wid = t >> 6;

    const int* bsum = (const int*)ws + IOFF_BSUM;
    if (t < 16) sb[t] = (t < c) ? bsum[(b << 4) + t] : 0;

    const int* mrow = mask + (size_t)blk * 2048;
    int4 m0 = *(const int4*)(mrow + t * 8);
    int4 m1 = *(const int4*)(mrow + t * 8 + 4);
    int mv[8] = {m0.x, m0.y, m0.z, m0.w, m1.x, m1.y, m1.z, m1.w};
    int cnt = 0;
    #pragma unroll
    for (int j = 0; j < 8; ++j) cnt += (mv[j] != 0);

    int x = cnt;
    #pragma unroll
    for (int off = 1; off < 64; off <<= 1) {
        int v = __shfl_up(x, off);
        if (lane >= off) x += v;
    }
    if (lane == 63) wsum[wid] = x;
    __syncthreads();
    int base = 0;
    #pragma unroll
    for (int w = 0; w < 4; ++w) base += (w < wid) ? wsum[w] : 0;
    int total = wsum[0] + wsum[1] + wsum[2] + wsum[3];
    int rloc = base + x - cnt;                   // exclusive prefix = local rank
    int boff = 0;
    #pragma unroll
    for (int i = 0; i < 16; ++i) boff += sb[i];

    float mu0 = ws[OFF_MU + b * 4 + 0], sd0 = ws[OFF_SD + b * 4 + 0];
    float mu1 = ws[OFF_MU + b * 4 + 1], sd1 = ws[OFF_SD + b * 4 + 1];
    float mu2 = ws[OFF_MU + b * 4 + 2], sd2 = ws[OFF_SD + b * 4 + 2];
    float mu3 = ws[OFF_MU + b * 4 + 3], sd3 = ws[OFF_SD + b * 4 + 3];
    for (int j = t; j < total; j += 256) {
        size_t idx = (size_t)b * KI + boff + j;
        float Ct = fmaxf((fC[idx] - mu0) / sd0, 0.f);
        float At = 1.f / (1.f + __expf(-((fA[idx] - mu1) / sd1)));
        float Dt = 1.f / (1.f + __expf(-((fD[idx] - mu2) / sd2)));
        float Bt = 1.f / (1.f + __expf(-((fB[idx] - mu3) / sd3)));
        float denom = fmaxf(1.f + 0.5f * (Dt + Bt), EPS);
        rfbuf[j] = fmaxf(Ct * At / denom, 0.f);
    }
    __syncthreads();
    float vr[8];
    #pragma unroll
    for (int j = 0; j < 8; ++j) {
        if (mv[j]) { vr[j] = rfbuf[rloc]; ++rloc; }
        else       { vr[j] = -1.f; }
    }
    float* rff = ws + OFF_RFF + (size_t)blk * 2048 + t * 8;
    *(float4*)(rff)     = *(float4*)(vr);
    *(float4*)(rff + 4) = *(float4*)(vr + 4);
}

// ---- per-(b,h)-quarter raw masked-softmax accumulation. The 128th (last)
//      finishing block of each batch computes the head roles (pos/neg top-k,
//      jax semantics: value desc, tie -> lower index, strictly-positive only)
//      and stores per-head gp/gn. No spin, no barrier — just extra work. ----
__global__ __launch_bounds__(256) void k_scores(const float* __restrict__ attn,
                                                float* __restrict__ ws) {
    int g = blockIdx.x, t = threadIdx.x;         // 2048 blocks: bh = g>>2, qtr = g&3
    int bh = g >> 2, qtr = g & 3;
    int b = bh >> 5;
    const float* xr  = attn + ((size_t)bh << 15) + ((size_t)qtr << 13);
    const float* rff = ws + OFF_RFF + ((size_t)b << 15) + ((size_t)qtr << 13);
    float S = 0.f, P = 0.f, N = 0.f;
    #pragma unroll
    for (int i = 0; i < 8; ++i) {
        int k = (i * 256 + t) * 4;
        float4 xs = *(const float4*)(xr + k);
        float4 rv = *(const float4*)(rff + k);
        float xa[4] = {xs.x, xs.y, xs.z, xs.w};
        float va[4] = {rv.x, rv.y, rv.z, rv.w};
        #pragma unroll
        for (int j = 0; j < 4; ++j) {
            float e = __expf(xa[j]);             // |x|<~6 -> no overflow, no max-sub
            bool on = va[j] >= 0.f;
            float rfv  = fmaxf(va[j], 0.f);
            float lrfv = on ? fmaxf(1.f - va[j], 0.f) : 0.f;
            S += on ? e : 0.f;
            P = fmaf(e, rfv, P);
            N = fmaf(e, lrfv, N);
        }
    }
    int lane = t & 63, wid = t >> 6;
    #pragma unroll
    for (int off = 32; off > 0; off >>= 1) {
        S += __shfl_down(S, off);
        P += __shfl_down(P, off);
        N += __shfl_down(N, off);
    }
    __shared__ float wS[4], wP[4], wN[4];
    __shared__ int s_last;
    if (lane == 0) { wS[wid] = S; wP[wid] = P; wN[wid] = N; }
    __syncthreads();
    if (t == 0) {
        atomicAdd(&ws[OFF_RAWS + bh], wS[0] + wS[1] + wS[2] + wS[3]);
        atomicAdd(&ws[OFF_RAWP + bh], wP[0] + wP[1] + wP[2] + wP[3]);
        atomicAdd(&ws[OFF_RAWN + bh], wN[0] + wN[1] + wN[2] + wN[3]);
        __threadfence();                         // release: sums before ticket
        int old = atomicAdd((int*)ws + IOFF_CNT + b, 1);
        s_last = (old == 127);                   // 128 blocks per batch
    }
    __syncthreads();
    if (!s_last) return;

    // ---- epilogue (one block per batch): head roles ----
    __threadfence();                             // acquire side
    __shared__ float ssp[NH], snv[NH];
    __shared__ int smp[NH];
    if (t < NH) {
        float S0 = __hip_atomic_load(&ws[OFF_RAWS + b * NH + t], __ATOMIC_RELAXED, __HIP_MEMORY_SCOPE_AGENT);
        float Pp = __hip_atomic_load(&ws[OFF_RAWP + b * NH + t], __ATOMIC_RELAXED, __HIP_MEMORY_SCOPE_AGENT);
        float Nn = __hip_atomic_load(&ws[OFF_RAWN + b * NH + t], __ATOMIC_RELAXED, __HIP_MEMORY_SCOPE_AGENT);
        ssp[t] = Pp / S0;
        snv[t] = Nn / S0;
    }
    __syncthreads();
    if (t < NH) {
        float sp = ssp[t];
        int c2 = 0;
        for (int j = 0; j < NH; ++j) { float o = ssp[j]; c2 += (o > sp) || (o == sp && j < t); }
        smp[t] = (c2 < KHEADS) && (sp > 0.f);
    }
    __syncthreads();
    if (t < NH && smp[t]) snv[t] = -INFINITY;
    __syncthreads();
    if (t < NH) {
        float gp = 0.f, gn = 0.f;
        if (smp[t]) gp = GAMMA;
        else {
            float nv = snv[t];
            int c2 = 0;
            for (int j = 0; j < NH; ++j) { float o = snv[j]; c2 += (o > nv) || (o == nv && j < t); }
            if ((c2 < KHEADS) && (nv > 0.f)) gn = GAMMA;
        }
        ws[OFF_GP + b * NH + t] = gp;            // later dispatch reads: visible
        ws[OFF_GN + b * NH + t] = gn;
    }
}

// ---- out = attn + gp*rf - gn*low_rf; pure streaming (roles precomputed).
//      Chunk swizzle keeps each block on the XCD whose L2/LLC path pulled
//      this attn region in k_scores; NT loads (last consumer of attn) and
//      NT stores (out never re-read) minimize cache displacement. ----
__global__ __launch_bounds__(256) void k_out(const float* __restrict__ attn,
        const float* __restrict__ ws, float* __restrict__ out) {
    unsigned int t = threadIdx.x;
    unsigned int j = blockIdx.x;                 // 8192 blocks
    unsigned int r = j & 7, q = j >> 3;
    unsigned int chunk = 8u * r + 64u * (q >> 3) + (q & 7);   // bijective, XCD-matched
    unsigned int flat = chunk * 2048 + t * 8;
    unsigned int bh = flat >> 15;                // uniform per block (2048 | 32768)
    unsigned int b  = bh >> 5;

    float gp = ws[OFF_GP + bh];                  // uniform scalar loads
    float gn = ws[OFF_GN + bh];

    const float* rff = ws + OFF_RFF + ((size_t)b << 15);
    unsigned int k = flat & (KF - 1);
    #pragma unroll
    for (int half8 = 0; half8 < 2; ++half8) {
        unsigned int f2 = flat + half8 * 4, k2 = k + half8 * 4;
        f4v xs = __builtin_nontemporal_load((const f4v*)(attn + f2));
        f4v rv = *(const f4v*)(rff + k2);
        float oa[4];
        #pragma unroll
        for (int jj = 0; jj < 4; ++jj) {
            float va = rv[jj];
            bool on = va >= 0.f;
            float rfv  = fmaxf(va, 0.f);
            float lrfv = on ? fmaxf(1.f - va, 0.f) : 0.f;
            oa[jj] = xs[jj] + gp * rfv - gn * lrfv;
        }
        f4v o = {oa[0], oa[1], oa[2], oa[3]};
        __builtin_nontemporal_store(o, (f4v*)(out + f2));
    }
}

extern "C" void kernel_launch(void* const* d_in, const int* in_sizes, int n_in,
                              void* d_out, int out_size, void* d_ws, size_t ws_size,
                              hipStream_t stream) {
    const float* attn = (const float*)d_in[0];   // f32 [B,H,KF]
    const int*   mask = (const int*)d_in[1];     // int32 [B,KF]
    const float* fC   = (const float*)d_in[2];   // f32 [B,KI]
    const float* fA   = (const float*)d_in[3];
    const float* fD   = (const float*)d_in[4];
    const float* fB   = (const float*)d_in[5];
    float* out = (float*)d_out;                  // f32 [B,H,KF]
    float* ws = (float*)d_ws;

    k_stats_cnt<<<320, 256, 0, stream>>>(fC, fA, fD, fB, mask, ws);
    k_rf_expand<<<256, 256, 0, stream>>>(fC, fA, fD, fB, mask, ws);
    k_scores   <<<2048, 256, 0, stream>>>(attn, ws);
    k_out      <<<B_SZ * NH * KF / 2048, 256, 0, stream>>>(attn, ws, out);
}

// Round 5
// 152.687 us; speedup vs baseline: 1.6377x; 1.6377x over previous
//
#include <hip/hip_runtime.h>
#include <math.h>

#define GAMMA 0.3f
#define EPS 1e-6f
#define B_SZ 16
#define NH 32
#define KF 32768
#define KI 16384
#define KHEADS 7   // ceil(0.2 * 32)

typedef float f4v __attribute__((ext_vector_type(4)));

// ---- workspace layout (float indices) ----
constexpr int OFF_MU    = 0;                    // 64  (b*4+f)
constexpr int OFF_SD    = 64;                   // 64
constexpr int OFF_RAWS  = 128;                  // 512  raw softmax denom per (b,h)
constexpr int OFF_RAWP  = 640;                  // 512  raw pos numerator
constexpr int OFF_RAWN  = 1152;                 // 512  raw neg numerator
constexpr int OFF_GP    = 1664;                 // 512  per-(b,h) pos gamma (0 or GAMMA)
constexpr int OFF_GN    = 2176;                 // 512  per-(b,h) neg gamma
constexpr int IOFF_BSUM = 2720;                 // 256 ints (per-2048-chunk mask counts)
constexpr int OFF_RFF   = 4096;                 // B*KF  rf expanded: rf>=0 on-mask, -1 off-mask

// LESSONS (journal):
//  prev-R6: cooperative grid.sync() fusion = ~120 µs barrier cost. NO.
//  R1: per-batch spin barrier + launch_bounds(256,4) regressed. NO spin sync.
//  R2: redundant per-block stats = latency disaster. Stats stay parallel.
//  R3 (best, 146.8): shuffle reductions, 2048-blk scores, swizzled NT k_out.
//  R4: __threadfence() in k_scores hot path = 120 µs (3x): device-scope fence
//      on gfx950 invalidates XCD L2 -> rff reuse dies. NO device-scope fences
//      in hot kernels. Cross-dispatch visibility is free — use extra dispatch.
//  R5: exact-R3 kernels + tiny k_roles dispatch (16 blocks) so k_out is pure
//      streaming (no per-block role preamble, no LDS).

// ---- blocks [0,64): per-(b,feat) mean/(std+eps) via wave-shuffle reduce;
//      blocks [64,320): 2048-int mask chunk counts (first 6 also zero accums) ----
__global__ __launch_bounds__(256) void k_stats_cnt(const float* __restrict__ fC,
        const float* __restrict__ fA, const float* __restrict__ fD,
        const float* __restrict__ fB, const int* __restrict__ mask,
        float* __restrict__ ws) {
    int bid = blockIdx.x, t = threadIdx.x;
    int lane = t & 63, wid = t >> 6;
    if (bid < 64) {
        int b = bid >> 2, f = bid & 3;
        const float* src;
        if (f == 0) src = fC; else if (f == 1) src = fA; else if (f == 2) src = fD; else src = fB;
        src += (size_t)b * KI;
        double s = 0.0, s2 = 0.0;
        #pragma unroll 4
        for (int i = t; i < KI / 4; i += 256) {
            float4 v = ((const float4*)src)[i];
            s  += (double)v.x + (double)v.y + (double)v.z + (double)v.w;
            s2 += (double)v.x * v.x + (double)v.y * v.y + (double)v.z * v.z + (double)v.w * v.w;
        }
        #pragma unroll
        for (int off = 32; off > 0; off >>= 1) {
            s  += __shfl_down(s, off);
            s2 += __shfl_down(s2, off);
        }
        __shared__ double w1[4], w2[4];
        if (lane == 0) { w1[wid] = s; w2[wid] = s2; }
        __syncthreads();
        if (t == 0) {
            double S1 = w1[0] + w1[1] + w1[2] + w1[3];
            double S2 = w2[0] + w2[1] + w2[2] + w2[3];
            double mu  = S1 * (1.0 / KI);
            double var = fmax(S2 * (1.0 / KI) - mu * mu, 0.0);
            ws[OFF_MU + bid] = (float)mu;
            ws[OFF_SD + bid] = (float)(sqrt(var) + (double)EPS);
        }
    } else {
        int cblk = bid - 64;                     // 0..255, 2048 ints each
        if (cblk < 6) ws[OFF_RAWS + cblk * 256 + t] = 0.f;   // zero 1536 accum floats
        const int* mrow = mask + (size_t)cblk * 2048;
        int4 m0 = *(const int4*)(mrow + t * 8);
        int4 m1 = *(const int4*)(mrow + t * 8 + 4);
        int cnt = (m0.x != 0) + (m0.y != 0) + (m0.z != 0) + (m0.w != 0)
                + (m1.x != 0) + (m1.y != 0) + (m1.z != 0) + (m1.w != 0);
        #pragma unroll
        for (int off = 32; off > 0; off >>= 1) cnt += __shfl_down(cnt, off);
        __shared__ int wc[4];
        if (lane == 0) wc[wid] = cnt;
        __syncthreads();
        if (t == 0) ((int*)ws)[IOFF_BSUM + cblk] = wc[0] + wc[1] + wc[2] + wc[3];
    }
}

// ---- fused rf-compute + expand-to-full-K (rf on-mask, -1 off-mask).
//      Image-token ranks of block (b,c) form the contiguous feat range
//      [boff, boff+total); wave-shuffle scan for local ranks. ----
__global__ __launch_bounds__(256) void k_rf_expand(const float* __restrict__ fC,
        const float* __restrict__ fA, const float* __restrict__ fD,
        const float* __restrict__ fB, const int* __restrict__ mask,
        float* __restrict__ ws) {
    __shared__ int sb[16];
    __shared__ int wsum[4];
    __shared__ float rfbuf[2048];
    int blk = blockIdx.x, t = threadIdx.x;       // blk = b*16 + c
    int b = blk >> 4, c = blk & 15;
    int lane = t & 63, wid = t >> 6;

    const int* bsum = (const int*)ws + IOFF_BSUM;
    if (t < 16) sb[t] = (t < c) ? bsum[(b << 4) + t] : 0;

    const int* mrow = mask + (size_t)blk * 2048;
    int4 m0 = *(const int4*)(mrow + t * 8);
    int4 m1 = *(const int4*)(mrow + t * 8 + 4);
    int mv[8] = {m0.x, m0.y, m0.z, m0.w, m1.x, m1.y, m1.z, m1.w};
    int cnt = 0;
    #pragma unroll
    for (int j = 0; j < 8; ++j) cnt += (mv[j] != 0);

    int x = cnt;
    #pragma unroll
    for (int off = 1; off < 64; off <<= 1) {
        int v = __shfl_up(x, off);
        if (lane >= off) x += v;
    }
    if (lane == 63) wsum[wid] = x;
    __syncthreads();
    int base = 0;
    #pragma unroll
    for (int w = 0; w < 4; ++w) base += (w < wid) ? wsum[w] : 0;
    int total = wsum[0] + wsum[1] + wsum[2] + wsum[3];
    int rloc = base + x - cnt;                   // exclusive prefix = local rank
    int boff = 0;
    #pragma unroll
    for (int i = 0; i < 16; ++i) boff += sb[i];

    float mu0 = ws[OFF_MU + b * 4 + 0], sd0 = ws[OFF_SD + b * 4 + 0];
    float mu1 = ws[OFF_MU + b * 4 + 1], sd1 = ws[OFF_SD + b * 4 + 1];
    float mu2 = ws[OFF_MU + b * 4 + 2], sd2 = ws[OFF_SD + b * 4 + 2];
    float mu3 = ws[OFF_MU + b * 4 + 3], sd3 = ws[OFF_SD + b * 4 + 3];
    for (int j = t; j < total; j += 256) {
        size_t idx = (size_t)b * KI + boff + j;
        float Ct = fmaxf((fC[idx] - mu0) / sd0, 0.f);
        float At = 1.f / (1.f + __expf(-((fA[idx] - mu1) / sd1)));
        float Dt = 1.f / (1.f + __expf(-((fD[idx] - mu2) / sd2)));
        float Bt = 1.f / (1.f + __expf(-((fB[idx] - mu3) / sd3)));
        float denom = fmaxf(1.f + 0.5f * (Dt + Bt), EPS);
        rfbuf[j] = fmaxf(Ct * At / denom, 0.f);
    }
    __syncthreads();
    float vr[8];
    #pragma unroll
    for (int j = 0; j < 8; ++j) {
        if (mv[j]) { vr[j] = rfbuf[rloc]; ++rloc; }
        else       { vr[j] = -1.f; }
    }
    float* rff = ws + OFF_RFF + (size_t)blk * 2048 + t * 8;
    *(float4*)(rff)     = *(float4*)(vr);
    *(float4*)(rff + 4) = *(float4*)(vr + 4);
}

// ---- per-(b,h)-quarter raw masked-softmax accumulation (branchless, no
//      max-sub: |x|<~6 -> e^x <= ~300; raw sums combined via atomicAdd).
//      2048 blocks (8/CU) for TLP on the attn read. NO fences (R4 lesson). ----
__global__ __launch_bounds__(256) void k_scores(const float* __restrict__ attn,
                                                float* __restrict__ ws) {
    int g = blockIdx.x, t = threadIdx.x;         // 2048 blocks: bh = g>>2, qtr = g&3
    int bh = g >> 2, qtr = g & 3;
    int b = bh >> 5;
    const float* xr  = attn + ((size_t)bh << 15) + ((size_t)qtr << 13);
    const float* rff = ws + OFF_RFF + ((size_t)b << 15) + ((size_t)qtr << 13);
    float S = 0.f, P = 0.f, N = 0.f;
    #pragma unroll
    for (int i = 0; i < 8; ++i) {
        int k = (i * 256 + t) * 4;
        float4 xs = *(const float4*)(xr + k);
        float4 rv = *(const float4*)(rff + k);
        float xa[4] = {xs.x, xs.y, xs.z, xs.w};
        float va[4] = {rv.x, rv.y, rv.z, rv.w};
        #pragma unroll
        for (int j = 0; j < 4; ++j) {
            float e = __expf(xa[j]);
            bool on = va[j] >= 0.f;
            float rfv  = fmaxf(va[j], 0.f);
            float lrfv = on ? fmaxf(1.f - va[j], 0.f) : 0.f;
            S += on ? e : 0.f;
            P = fmaf(e, rfv, P);
            N = fmaf(e, lrfv, N);
        }
    }
    int lane = t & 63, wid = t >> 6;
    #pragma unroll
    for (int off = 32; off > 0; off >>= 1) {
        S += __shfl_down(S, off);
        P += __shfl_down(P, off);
        N += __shfl_down(N, off);
    }
    __shared__ float wS[4], wP[4], wN[4];
    if (lane == 0) { wS[wid] = S; wP[wid] = P; wN[wid] = N; }
    __syncthreads();
    if (t == 0) {
        atomicAdd(&ws[OFF_RAWS + bh], wS[0] + wS[1] + wS[2] + wS[3]);
        atomicAdd(&ws[OFF_RAWP + bh], wP[0] + wP[1] + wP[2] + wP[3]);
        atomicAdd(&ws[OFF_RAWN + bh], wN[0] + wN[1] + wN[2] + wN[3]);
    }
}

// ---- tiny per-batch role computation (16 blocks x 64 threads). Reads the
//      finished raw sums (visible at dispatch boundary — no fences needed),
//      computes pos/neg top-k (jax semantics: value desc, tie -> lower index,
//      strictly-positive only), stores per-(b,h) gp/gn. ----
__global__ __launch_bounds__(64) void k_roles(float* __restrict__ ws) {
    int b = blockIdx.x, t = threadIdx.x;
    __shared__ float ssp[NH], snv[NH];
    __shared__ int smp[NH];
    if (t < NH) {
        float S0 = ws[OFF_RAWS + b * NH + t];
        ssp[t] = ws[OFF_RAWP + b * NH + t] / S0;
        snv[t] = ws[OFF_RAWN + b * NH + t] / S0;
    }
    __syncthreads();
    if (t < NH) {
        float sp = ssp[t];
        int c2 = 0;
        for (int j = 0; j < NH; ++j) { float o = ssp[j]; c2 += (o > sp) || (o == sp && j < t); }
        smp[t] = (c2 < KHEADS) && (sp > 0.f);
    }
    __syncthreads();
    if (t < NH && smp[t]) snv[t] = -INFINITY;
    __syncthreads();
    if (t < NH) {
        float gp = 0.f, gn = 0.f;
        if (smp[t]) gp = GAMMA;
        else {
            float nv = snv[t];
            int c2 = 0;
            for (int j = 0; j < NH; ++j) { float o = snv[j]; c2 += (o > nv) || (o == nv && j < t); }
            if ((c2 < KHEADS) && (nv > 0.f)) gn = GAMMA;
        }
        ws[OFF_GP + b * NH + t] = gp;
        ws[OFF_GN + b * NH + t] = gn;
    }
}

// ---- out = attn + gp*rf - gn*low_rf; pure streaming (roles precomputed,
//      zero LDS, zero barriers). Chunk swizzle keeps each block on the XCD
//      whose L2 path pulled this attn region in k_scores; NT stores (out
//      never re-read) avoid displacing LLC-resident attn. ----
__global__ __launch_bounds__(256) void k_out(const float* __restrict__ attn,
        const float* __restrict__ ws, float* __restrict__ out) {
    unsigned int t = threadIdx.x;
    unsigned int j = blockIdx.x;                 // 8192 blocks
    unsigned int r = j & 7, q = j >> 3;
    unsigned int chunk = 8u * r + 64u * (q >> 3) + (q & 7);   // bit-permute, bijective
    unsigned int flat = chunk * 2048 + t * 8;
    unsigned int bh = flat >> 15;                // uniform per block (2048 | 32768)
    unsigned int b  = bh >> 5;

    float gp = ws[OFF_GP + bh];                  // uniform scalar loads
    float gn = ws[OFF_GN + bh];

    const float* rff = ws + OFF_RFF + ((size_t)b << 15);
    unsigned int k = flat & (KF - 1);
    #pragma unroll
    for (int half8 = 0; half8 < 2; ++half8) {
        unsigned int f2 = flat + half8 * 4, k2 = k + half8 * 4;
        float4 xs = *(const float4*)(attn + f2);
        float4 rv = *(const float4*)(rff + k2);
        float xa[4] = {xs.x, xs.y, xs.z, xs.w};
        float va[4] = {rv.x, rv.y, rv.z, rv.w};
        float oa[4];
        #pragma unroll
        for (int jj = 0; jj < 4; ++jj) {
            bool on = va[jj] >= 0.f;
            float rfv  = fmaxf(va[jj], 0.f);
            float lrfv = on ? fmaxf(1.f - va[jj], 0.f) : 0.f;
            oa[jj] = xa[jj] + gp * rfv - gn * lrfv;
        }
        f4v o = {oa[0], oa[1], oa[2], oa[3]};
        __builtin_nontemporal_store(o, (f4v*)(out + f2));
    }
}

extern "C" void kernel_launch(void* const* d_in, const int* in_sizes, int n_in,
                              void* d_out, int out_size, void* d_ws, size_t ws_size,
                              hipStream_t stream) {
    const float* attn = (const float*)d_in[0];   // f32 [B,H,KF]
    const int*   mask = (const int*)d_in[1];     // int32 [B,KF]
    const float* fC   = (const float*)d_in[2];   // f32 [B,KI]
    const float* fA   = (const float*)d_in[3];
    const float* fD   = (const float*)d_in[4];
    const float* fB   = (const float*)d_in[5];
    float* out = (float*)d_out;                  // f32 [B,H,KF]
    float* ws = (float*)d_ws;

    k_stats_cnt<<<320, 256, 0, stream>>>(fC, fA, fD, fB, mask, ws);
    k_rf_expand<<<256, 256, 0, stream>>>(fC, fA, fD, fB, mask, ws);
    k_scores   <<<2048, 256, 0, stream>>>(attn, ws);
    k_roles    <<<B_SZ, 64, 0, stream>>>(ws);
    k_out      <<<B_SZ * NH * KF / 2048, 256, 0, stream>>>(attn, ws, out);
}

// Round 6
// 147.585 us; speedup vs baseline: 1.6943x; 1.0346x over previous
//
#include <hip/hip_runtime.h>
#include <math.h>

#define GAMMA 0.3f
#define EPS 1e-6f
#define B_SZ 16
#define NH 32
#define KF 32768
#define KI 16384
#define KHEADS 7   // ceil(0.2 * 32)

typedef float f4v __attribute__((ext_vector_type(4)));

// ---- workspace layout (float indices) ----
constexpr int OFF_MU    = 0;                    // 64  (b*4+f)
constexpr int OFF_SD    = 64;                   // 64
constexpr int OFF_RAWS  = 128;                  // 512  raw softmax denom per (b,h)
constexpr int OFF_RAWP  = 640;                  // 512  raw pos numerator
constexpr int OFF_RAWN  = 1152;                 // 512  raw neg numerator
constexpr int IOFF_BSUM = 1664;                 // 256 ints (per-2048-chunk mask counts)
constexpr int OFF_RFF   = 4096;                 // B*KF  rf expanded: rf>=0 on-mask, -1 off-mask

// LESSONS (journal):
//  prev-R6: cooperative grid.sync() fusion = ~120 µs barrier cost. NO.
//  R1: per-batch spin barrier + launch_bounds(256,4) regressed (VGPR cap 64
//      -> attn re-loaded; barrier serialized tail). NO spin/global sync.
//  R2: fusing stats into expand (redundant serial per-block stats) = 47.8 µs,
//      9% occupancy, latency-bound. Stats stay parallel; 4-dispatch skeleton.
//  R3 (BEST, 146.8): shuffle reductions, 2048-blk scores, swizzled NT k_out.
//  R4: __threadfence() in k_scores hot path = 120 µs (3x): device-scope fence
//      on gfx950 kills XCD-L2 reuse. NO device-scope fences in hot kernels.
//  R5: separate k_roles dispatch = +2-3 µs net (dispatch boundary ~2-4 µs >
//      R3's redundant per-block preamble). Redundant cheap compute > launch.
//  Rejected: inlining rf into k_scores (32x redundant feat/mask L2 traffic
//      ~+6 µs cancels the ~3-4 µs dispatch saving).
//  Overhead model: ~82 µs poison fills + ~35 µs reset memsets/gaps (harness-
//      fixed) + ~45 µs own kernels (floor ~33). This IS the floor structure.

// ---- blocks [0,64): per-(b,feat) mean/(std+eps) via wave-shuffle reduce;
//      blocks [64,320): 2048-int mask chunk counts (first 6 also zero accums) ----
__global__ __launch_bounds__(256) void k_stats_cnt(const float* __restrict__ fC,
        const float* __restrict__ fA, const float* __restrict__ fD,
        const float* __restrict__ fB, const int* __restrict__ mask,
        float* __restrict__ ws) {
    int bid = blockIdx.x, t = threadIdx.x;
    int lane = t & 63, wid = t >> 6;
    if (bid < 64) {
        int b = bid >> 2, f = bid & 3;
        const float* src;
        if (f == 0) src = fC; else if (f == 1) src = fA; else if (f == 2) src = fD; else src = fB;
        src += (size_t)b * KI;
        double s = 0.0, s2 = 0.0;
        #pragma unroll 4
        for (int i = t; i < KI / 4; i += 256) {
            float4 v = ((const float4*)src)[i];
            s  += (double)v.x + (double)v.y + (double)v.z + (double)v.w;
            s2 += (double)v.x * v.x + (double)v.y * v.y + (double)v.z * v.z + (double)v.w * v.w;
        }
        #pragma unroll
        for (int off = 32; off > 0; off >>= 1) {
            s  += __shfl_down(s, off);
            s2 += __shfl_down(s2, off);
        }
        __shared__ double w1[4], w2[4];
        if (lane == 0) { w1[wid] = s; w2[wid] = s2; }
        __syncthreads();
        if (t == 0) {
            double S1 = w1[0] + w1[1] + w1[2] + w1[3];
            double S2 = w2[0] + w2[1] + w2[2] + w2[3];
            double mu  = S1 * (1.0 / KI);
            double var = fmax(S2 * (1.0 / KI) - mu * mu, 0.0);
            ws[OFF_MU + bid] = (float)mu;
            ws[OFF_SD + bid] = (float)(sqrt(var) + (double)EPS);
        }
    } else {
        int cblk = bid - 64;                     // 0..255, 2048 ints each
        if (cblk < 6) ws[OFF_RAWS + cblk * 256 + t] = 0.f;   // zero 1536 accum floats
        const int* mrow = mask + (size_t)cblk * 2048;
        int4 m0 = *(const int4*)(mrow + t * 8);
        int4 m1 = *(const int4*)(mrow + t * 8 + 4);
        int cnt = (m0.x != 0) + (m0.y != 0) + (m0.z != 0) + (m0.w != 0)
                + (m1.x != 0) + (m1.y != 0) + (m1.z != 0) + (m1.w != 0);
        #pragma unroll
        for (int off = 32; off > 0; off >>= 1) cnt += __shfl_down(cnt, off);
        __shared__ int wc[4];
        if (lane == 0) wc[wid] = cnt;
        __syncthreads();
        if (t == 0) ((int*)ws)[IOFF_BSUM + cblk] = wc[0] + wc[1] + wc[2] + wc[3];
    }
}

// ---- fused rf-compute + expand-to-full-K (rf on-mask, -1 off-mask).
//      Image-token ranks of block (b,c) form the contiguous feat range
//      [boff, boff+total); wave-shuffle scan for local ranks. ----
__global__ __launch_bounds__(256) void k_rf_expand(const float* __restrict__ fC,
        const float* __restrict__ fA, const float* __restrict__ fD,
        const float* __restrict__ fB, const int* __restrict__ mask,
        float* __restrict__ ws) {
    __shared__ int sb[16];
    __shared__ int wsum[4];
    __shared__ float rfbuf[2048];
    int blk = blockIdx.x, t = threadIdx.x;       // blk = b*16 + c
    int b = blk >> 4, c = blk & 15;
    int lane = t & 63, wid = t >> 6;

    const int* bsum = (const int*)ws + IOFF_BSUM;
    if (t < 16) sb[t] = (t < c) ? bsum[(b << 4) + t] : 0;

    const int* mrow = mask + (size_t)blk * 2048;
    int4 m0 = *(const int4*)(mrow + t * 8);
    int4 m1 = *(const int4*)(mrow + t * 8 + 4);
    int mv[8] = {m0.x, m0.y, m0.z, m0.w, m1.x, m1.y, m1.z, m1.w};
    int cnt = 0;
    #pragma unroll
    for (int j = 0; j < 8; ++j) cnt += (mv[j] != 0);

    int x = cnt;
    #pragma unroll
    for (int off = 1; off < 64; off <<= 1) {
        int v = __shfl_up(x, off);
        if (lane >= off) x += v;
    }
    if (lane == 63) wsum[wid] = x;
    __syncthreads();
    int base = 0;
    #pragma unroll
    for (int w = 0; w < 4; ++w) base += (w < wid) ? wsum[w] : 0;
    int total = wsum[0] + wsum[1] + wsum[2] + wsum[3];
    int rloc = base + x - cnt;                   // exclusive prefix = local rank
    int boff = 0;
    #pragma unroll
    for (int i = 0; i < 16; ++i) boff += sb[i];

    float mu0 = ws[OFF_MU + b * 4 + 0], sd0 = ws[OFF_SD + b * 4 + 0];
    float mu1 = ws[OFF_MU + b * 4 + 1], sd1 = ws[OFF_SD + b * 4 + 1];
    float mu2 = ws[OFF_MU + b * 4 + 2], sd2 = ws[OFF_SD + b * 4 + 2];
    float mu3 = ws[OFF_MU + b * 4 + 3], sd3 = ws[OFF_SD + b * 4 + 3];
    for (int j = t; j < total; j += 256) {
        size_t idx = (size_t)b * KI + boff + j;
        float Ct = fmaxf((fC[idx] - mu0) / sd0, 0.f);
        float At = 1.f / (1.f + __expf(-((fA[idx] - mu1) / sd1)));
        float Dt = 1.f / (1.f + __expf(-((fD[idx] - mu2) / sd2)));
        float Bt = 1.f / (1.f + __expf(-((fB[idx] - mu3) / sd3)));
        float denom = fmaxf(1.f + 0.5f * (Dt + Bt), EPS);
        rfbuf[j] = fmaxf(Ct * At / denom, 0.f);
    }
    __syncthreads();
    float vr[8];
    #pragma unroll
    for (int j = 0; j < 8; ++j) {
        if (mv[j]) { vr[j] = rfbuf[rloc]; ++rloc; }
        else       { vr[j] = -1.f; }
    }
    float* rff = ws + OFF_RFF + (size_t)blk * 2048 + t * 8;
    *(float4*)(rff)     = *(float4*)(vr);
    *(float4*)(rff + 4) = *(float4*)(vr + 4);
}

// ---- per-(b,h)-quarter raw masked-softmax accumulation (branchless, no
//      max-sub: |x|<~6 -> e^x <= ~300; raw sums combined via atomicAdd).
//      2048 blocks (8/CU) for TLP on the cold 64 MB attn read. ----
__global__ __launch_bounds__(256) void k_scores(const float* __restrict__ attn,
                                                float* __restrict__ ws) {
    int g = blockIdx.x, t = threadIdx.x;         // 2048 blocks: bh = g>>2, qtr = g&3
    int bh = g >> 2, qtr = g & 3;
    int b = bh >> 5;
    const float* xr  = attn + ((size_t)bh << 15) + ((size_t)qtr << 13);
    const float* rff = ws + OFF_RFF + ((size_t)b << 15) + ((size_t)qtr << 13);
    float S = 0.f, P = 0.f, N = 0.f;
    #pragma unroll
    for (int i = 0; i < 8; ++i) {
        int k = (i * 256 + t) * 4;
        float4 xs = *(const float4*)(xr + k);
        float4 rv = *(const float4*)(rff + k);
        float xa[4] = {xs.x, xs.y, xs.z, xs.w};
        float va[4] = {rv.x, rv.y, rv.z, rv.w};
        #pragma unroll
        for (int j = 0; j < 4; ++j) {
            float e = __expf(xa[j]);
            bool on = va[j] >= 0.f;
            float rfv  = fmaxf(va[j], 0.f);
            float lrfv = on ? fmaxf(1.f - va[j], 0.f) : 0.f;
            S += on ? e : 0.f;
            P = fmaf(e, rfv, P);
            N = fmaf(e, lrfv, N);
        }
    }
    int lane = t & 63, wid = t >> 6;
    #pragma unroll
    for (int off = 32; off > 0; off >>= 1) {
        S += __shfl_down(S, off);
        P += __shfl_down(P, off);
        N += __shfl_down(N, off);
    }
    __shared__ float wS[4], wP[4], wN[4];
    if (lane == 0) { wS[wid] = S; wP[wid] = P; wN[wid] = N; }
    __syncthreads();
    if (t == 0) {
        atomicAdd(&ws[OFF_RAWS + bh], wS[0] + wS[1] + wS[2] + wS[3]);
        atomicAdd(&ws[OFF_RAWP + bh], wP[0] + wP[1] + wP[2] + wP[3]);
        atomicAdd(&ws[OFF_RAWN + bh], wN[0] + wN[1] + wN[2] + wN[3]);
    }
}

// ---- out = attn + gp*rf - gn*low_rf; per-block redundant top-k (jax top_k
//      semantics: value desc, tie -> lower index, strictly-positive only).
//      Chunk swizzle puts each block on the XCD whose L2 read this attn
//      region in k_scores (scores block g covers 8 chunks; XCD = g%8).
//      Nontemporal out stores keep attn LLC-resident for trailing blocks. ----
__global__ __launch_bounds__(256) void k_out(const float* __restrict__ attn,
        const float* __restrict__ ws, float* __restrict__ out) {
    unsigned int t = threadIdx.x;
    unsigned int j = blockIdx.x;                 // 8192 blocks
    unsigned int r = j & 7, q = j >> 3;
    unsigned int chunk = 8u * r + 64u * (q >> 3) + (q & 7);   // bijective, XCD-matched
    unsigned int flat = chunk * 2048 + t * 8;
    unsigned int bh = flat >> 15;                // uniform per block (2048 | 32768)
    unsigned int b  = bh >> 5;
    unsigned int h  = bh & 31;

    __shared__ float ssp[NH], snv[NH];
    __shared__ int smp[NH];
    __shared__ float s_gp, s_gn;
    if (t < NH) {
        float S0 = ws[OFF_RAWS + b * NH + t];
        ssp[t] = ws[OFF_RAWP + b * NH + t] / S0;
        snv[t] = ws[OFF_RAWN + b * NH + t] / S0;
    }
    __syncthreads();
    if (t < NH) {
        float sp = ssp[t];
        int cnt = 0;
        for (int jj = 0; jj < NH; ++jj) { float o = ssp[jj]; cnt += (o > sp) || (o == sp && jj < (int)t); }
        smp[t] = (cnt < KHEADS) && (sp > 0.f);
    }
    __syncthreads();
    if (t < NH && smp[t]) snv[t] = -INFINITY;
    __syncthreads();
    if (t == 0) {
        float gp = 0.f, gn = 0.f;
        if (smp[h]) gp = GAMMA;
        else {
            float nv = snv[h];
            int cnt = 0;
            for (int jj = 0; jj < NH; ++jj) { float o = snv[jj]; cnt += (o > nv) || (o == nv && jj < (int)h); }
            if ((cnt < KHEADS) && (nv > 0.f)) gn = GAMMA;
        }
        s_gp = gp; s_gn = gn;
    }
    __syncthreads();

    float gp = s_gp, gn = s_gn;
    const float* rff = ws + OFF_RFF + ((size_t)b << 15);
    unsigned int k = flat & (KF - 1);
    #pragma unroll
    for (int half8 = 0; half8 < 2; ++half8) {
        unsigned int f2 = flat + half8 * 4, k2 = k + half8 * 4;
        float4 xs = *(const float4*)(attn + f2);
        float4 rv = *(const float4*)(rff + k2);
        float va[4] = {rv.x, rv.y, rv.z, rv.w};
        float xa[4] = {xs.x, xs.y, xs.z, xs.w};
        float oa[4];
        #pragma unroll
        for (int jj = 0; jj < 4; ++jj) {
            bool on = va[jj] >= 0.f;
            float rfv  = fmaxf(va[jj], 0.f);
            float lrfv = on ? fmaxf(1.f - va[jj], 0.f) : 0.f;
            oa[jj] = xa[jj] + gp * rfv - gn * lrfv;
        }
        f4v o = {oa[0], oa[1], oa[2], oa[3]};
        __builtin_nontemporal_store(o, (f4v*)(out + f2));
    }
}

extern "C" void kernel_launch(void* const* d_in, const int* in_sizes, int n_in,
                              void* d_out, int out_size, void* d_ws, size_t ws_size,
                              hipStream_t stream) {
    const float* attn = (const float*)d_in[0];   // f32 [B,H,KF]
    const int*   mask = (const int*)d_in[1];     // int32 [B,KF]
    const float* fC   = (const float*)d_in[2];   // f32 [B,KI]
    const float* fA   = (const float*)d_in[3];
    const float* fD   = (const float*)d_in[4];
    const float* fB   = (const float*)d_in[5];
    float* out = (float*)d_out;                  // f32 [B,H,KF]
    float* ws = (float*)d_ws;

    k_stats_cnt<<<320, 256, 0, stream>>>(fC, fA, fD, fB, mask, ws);
    k_rf_expand<<<256, 256, 0, stream>>>(fC, fA, fD, fB, mask, ws);
    k_scores   <<<2048, 256, 0, stream>>>(attn, ws);
    k_out      <<<B_SZ * NH * KF / 2048, 256, 0, stream>>>(attn, ws, out);
}